// Round 1
// baseline (2586.204 us; speedup 1.0000x reference)
//
#include <hip/hip_runtime.h>
#include <math.h>
#include <float.h>

#define H 1080
#define W 1920
#define NPART 25
#define NCH 26          // heatmap channels in memory (NPART+1)
#define NLIMB 26
#define KTOP 32
#define MID 10
#define RAD 12

// Tile geometry for fused blur+peak kernel
#define TH 32
#define TW 64
#define LR (TH + 2*RAD + 2)   // 58 input rows
#define LC (TW + 2*RAD + 2)   // 90 input cols
#define VR (TH + 2)           // 34 vertical-blur rows
#define VC (TW + 2*RAD + 2)   // 90 vertical-blur cols
#define SR (TH + 2)           // 34 sm rows
#define SC (TW + 2)           // 66 sm cols

// Output layout (floats): px[25*32] py[25*32] score[25*32] mask[25*32] conn[26*32*32]
#define OFF_PY   800
#define OFF_SC   1600
#define OFF_MK   2400
#define OFF_CONN 3200

__device__ __constant__ int LIMBS_d[NLIMB * 2] = {
    1,8, 1,2, 1,5, 2,3, 3,4, 5,6, 6,7, 8,9, 9,10, 10,11, 8,12, 12,13, 13,14,
    1,0, 0,15, 15,16, 0,17, 0,18, 14,19, 19,20, 14,21, 11,22, 22,23, 11,24, 2,17, 5,18
};

__device__ __forceinline__ int symH(int y) {
    if (y < 0) return -1 - y;
    if (y >= H) return 2 * H - 1 - y;
    return y;
}
__device__ __forceinline__ int symW(int x) {
    if (x < 0) return -1 - x;
    if (x >= W) return 2 * W - 1 - x;
    return x;
}

// ---------------------------------------------------------------------------
// Kernel A: fused separable gaussian blur (f64 accumulation) + NMS peak detect
// grid: (25 channels fastest for L2 reuse of channel-interleaved lines, 30 x-tiles, 34 y-tiles)
// ---------------------------------------------------------------------------
__global__ __launch_bounds__(256) void blur_peaks(
    const float* __restrict__ hm,
    float* __restrict__ cval, int* __restrict__ cidx,
    int* __restrict__ counters, int cap)
{
    __shared__ float  in_t[LR][LC];      // raw heatmap tile (also the peak scores)
    __shared__ double v[VR][VC];         // vertical blur result
    __shared__ double smv[SR][SC];       // full blur result
    __shared__ double wgt[2 * RAD + 1];
    __shared__ double wsum;

    const int tid = threadIdx.x;
    const int ch  = blockIdx.x;
    const int x0  = blockIdx.y * TW;
    const int y0  = blockIdx.z * TH;

    // gaussian weights in f64 (matches np float64 reference to ~1 ulp)
    if (tid < 2 * RAD + 1) {
        double t = (double)(tid - RAD) / 3.0;
        wgt[tid] = exp(-0.5 * t * t);
    }
    __syncthreads();
    if (tid == 0) {
        double s = 0.0;
        for (int i = 0; i < 2 * RAD + 1; i++) s += wgt[i];
        wsum = s;
    }
    __syncthreads();
    if (tid < 2 * RAD + 1) wgt[tid] /= wsum;

    // load input tile with symmetric padding (channels-last gather)
    for (int i = tid; i < LR * LC; i += 256) {
        int r = i / LC, c = i % LC;
        int gy = symH(y0 - RAD - 1 + r);
        int gx = symW(x0 - RAD - 1 + c);
        in_t[r][c] = hm[((size_t)gy * W + gx) * NCH + ch];
    }
    __syncthreads();

    // vertical pass (f64)
    for (int i = tid; i < VR * VC; i += 256) {
        int r = i / VC, c = i % VC;
        double acc = 0.0;
        #pragma unroll
        for (int t = 0; t < 2 * RAD + 1; t++)
            acc = fma(wgt[t], (double)in_t[r + t][c], acc);
        v[r][c] = acc;
    }
    __syncthreads();

    // horizontal pass (f64); out-of-image rows/cols forced to 0 (matches the
    // z_row / z_col zero-concat in the reference neighbor comparison)
    for (int i = tid; i < SR * SC; i += 256) {
        int r = i / SC, cc = i % SC;
        int gy = y0 - 1 + r;
        int gx = x0 - 1 + cc;
        double acc = 0.0;
        if (gy >= 0 && gy < H && gx >= 0 && gx < W) {
            #pragma unroll
            for (int t = 0; t < 2 * RAD + 1; t++)
                acc = fma(wgt[t], v[r][cc + t], acc);
        }
        smv[r][cc] = acc;
    }
    __syncthreads();

    // peak detection + candidate emission
    for (int i = tid; i < TH * TW; i += 256) {
        int ly = i / TW, lx = i % TW;
        int gy = y0 + ly, gx = x0 + lx;
        if (gy >= H || gx >= W) continue;
        double s = smv[ly + 1][lx + 1];
        if (s > 0.1 &&
            s >= smv[ly][lx + 1] && s >= smv[ly + 2][lx + 1] &&
            s >= smv[ly + 1][lx] && s >= smv[ly + 1][lx + 2]) {
            float val = in_t[ly + RAD + 1][lx + RAD + 1];  // ORIGINAL map value
            int pos = atomicAdd(&counters[ch], 1);
            if (pos < cap) {
                cval[(size_t)ch * cap + pos] = val;
                cidx[(size_t)ch * cap + pos] = gy * W + gx;
            }
        }
    }
}

// ---------------------------------------------------------------------------
// Kernel B: per-channel exact top-32 by (value desc, index asc)
// ---------------------------------------------------------------------------
#define BT 128
__global__ __launch_bounds__(BT) void topk_kernel(
    const float* __restrict__ cval, const int* __restrict__ cidx,
    const int* __restrict__ counters, int cap, float* __restrict__ out)
{
    __shared__ unsigned long long lk[KTOP * BT];  // per-thread sorted lists (desc)
    __shared__ unsigned long long rk[BT];
    __shared__ int rw[BT];
    __shared__ int winner;

    const int tid = threadIdx.x;
    const int ch  = blockIdx.x;
    int n = counters[ch];
    if (n > cap) n = cap;

    int cnt = 0;
    for (int j = tid; j < n; j += BT) {
        float v = cval[(size_t)ch * cap + j];
        unsigned int u = __float_as_uint(v);
        u = (u & 0x80000000u) ? ~u : (u | 0x80000000u);   // monotonic key
        unsigned long long key =
            ((unsigned long long)u << 32) |
            (unsigned int)(0xFFFFFFFFu - (unsigned int)cidx[(size_t)ch * cap + j]);
        if (cnt == KTOP) {
            if (key <= lk[(KTOP - 1) * BT + tid]) continue;
            cnt = KTOP - 1;
        }
        int i = cnt;
        while (i > 0 && key > lk[(i - 1) * BT + tid]) {
            lk[i * BT + tid] = lk[(i - 1) * BT + tid];
            i--;
        }
        lk[i * BT + tid] = key;
        cnt++;
    }
    int cur = 0;
    __syncthreads();

    for (int k = 0; k < KTOP; k++) {
        rk[tid] = (cur < cnt) ? lk[cur * BT + tid] : 0ULL;
        rw[tid] = tid;
        __syncthreads();
        for (int s = BT / 2; s > 0; s >>= 1) {
            if (tid < s) {
                if (rk[tid + s] > rk[tid]) { rk[tid] = rk[tid + s]; rw[tid] = rw[tid + s]; }
            }
            __syncthreads();
        }
        if (tid == 0) {
            winner = rw[0];
            unsigned long long bk = rk[0];
            float px, py, sc, mk;
            if (bk == 0ULL) {
                // fewer than K peaks: emulate top_k on the -1e9 filler (lowest flat idx)
                int fake = k - n; if (fake < 0) fake = 0;
                px = (float)(fake % W); py = (float)(fake / W); sc = 0.f; mk = 0.f;
            } else {
                unsigned int u = (unsigned int)(bk >> 32);
                unsigned int fb = (u & 0x80000000u) ? (u ^ 0x80000000u) : ~u;
                float v = __uint_as_float(fb);
                int idx = (int)(0xFFFFFFFFu - (unsigned int)(bk & 0xFFFFFFFFu));
                px = (float)(idx % W); py = (float)(idx / W); sc = v; mk = 1.f;
            }
            out[ch * KTOP + k]          = px;
            out[OFF_PY + ch * KTOP + k] = py;
            out[OFF_SC + ch * KTOP + k] = sc;
            out[OFF_MK + ch * KTOP + k] = mk;
        }
        __syncthreads();
        if (tid == winner && cur < cnt) cur++;
        __syncthreads();
    }
}

// ---------------------------------------------------------------------------
// Kernel C: limb connection scores (26 x 32 x 32)
// ---------------------------------------------------------------------------
__global__ __launch_bounds__(1024) void limbs_kernel(
    const float* __restrict__ pk, const float* __restrict__ paf,
    float* __restrict__ out)
{
    const int l = blockIdx.x;
    const int tid = threadIdx.x;
    const int i = tid >> 5;   // A-peak index
    const int j = tid & 31;   // B-peak index
    const int A = LIMBS_d[2 * l], B = LIMBS_d[2 * l + 1];

    float ax = pk[A * KTOP + i],          ay = pk[OFF_PY + A * KTOP + i];
    float ma = pk[OFF_MK + A * KTOP + i];
    float bx = pk[B * KTOP + j],          by = pk[OFF_PY + B * KTOP + j];
    float mb = pk[OFF_MK + B * KTOP + j];

    float vx = bx - ax, vy = by - ay;
    float norm = sqrtf(vx * vx + vy * vy) + 1e-10f;
    float ux = vx / norm, uy = vy / norm;

    const float step = 1.0f / 9.0f;
    float sum = 0.f;
    #pragma unroll
    for (int m = 0; m < MID; m++) {
        float t = (float)m * step;                 // t[9] rounds to exactly 1.0f
        int sx = (int)rintf(ax + vx * t);          // RNE == jnp.round
        int sy = (int)rintf(ay + vy * t);
        const float* p = paf + ((size_t)sy * W + sx) * (2 * NLIMB) + 2 * l;
        sum += p[0] * ux + p[1] * uy;
    }
    float score = sum / (float)MID;
    score = score < 0.f ? 0.f : (score > 1.f ? 1.f : score);
    float res = (ma != 0.f && mb != 0.f) ? score : 0.f;
    out[OFF_CONN + l * (KTOP * KTOP) + i * KTOP + j] = res;
}

// ---------------------------------------------------------------------------
extern "C" void kernel_launch(void* const* d_in, const int* in_sizes, int n_in,
                              void* d_out, int out_size, void* d_ws, size_t ws_size,
                              hipStream_t stream)
{
    const float* hm  = (const float*)d_in[0];
    const float* paf = (const float*)d_in[1];
    float* out = (float*)d_out;

    // ws layout: [0,256) counters, then cval[25*cap] f32, cidx[25*cap] i32
    size_t avail = ws_size > 256 ? ws_size - 256 : 0;
    long long capll = (long long)(avail / ((size_t)NPART * 8));
    int cap = capll > 65536 ? 65536 : (int)capll;
    if (cap < 1) cap = 1;

    int*   counters = (int*)d_ws;
    float* cval = (float*)((char*)d_ws + 256);
    int*   cidx = (int*)(cval + (size_t)NPART * cap);

    hipMemsetAsync(d_ws, 0, 256, stream);

    dim3 gA(NPART, (W + TW - 1) / TW, (H + TH - 1) / TH);
    blur_peaks<<<gA, 256, 0, stream>>>(hm, cval, cidx, counters, cap);
    topk_kernel<<<NPART, BT, 0, stream>>>(cval, cidx, counters, cap, out);
    limbs_kernel<<<NLIMB, 1024, 0, stream>>>(out, paf, out);
}